// Round 1
// baseline (627.009 us; speedup 1.0000x reference)
//
#include <hip/hip_runtime.h>

// mute(x): m,e = frexp(x); if e > 1 return m else x.
// For finite normals: e > 1  <=>  biased exponent >= 128 (|x| >= 2).
// Mantissa with frexp convention = same sign+mantissa bits, exponent field = 126 (2^-1).
__device__ __forceinline__ float mute1(float v) {
    unsigned b = __float_as_uint(v);
    unsigned e = (b >> 23) & 0xffu;
    float m = __uint_as_float((b & 0x807FFFFFu) | 0x3F000000u);
    return (e >= 128u) ? m : v;
}

// One thread per float4. Image is 28x28 = 784 floats = 196 float4s; each float4
// sits entirely within one row h, covering w = 4*j .. 4*j+3.
__global__ __launch_bounds__(256) void mute_kernel(
    const float4* __restrict__ x, float4* __restrict__ out,
    const int* __restrict__ rows, const int* __restrict__ cols, int n4)
{
    // rows/cols pointers are kernel-arg-uniform with constant offsets -> scalar loads.
    unsigned row_mask = (1u << rows[0]) | (1u << rows[1]) | (1u << rows[2]) | (1u << rows[3]);
    unsigned col_mask = (1u << cols[0]) | (1u << cols[1]) | (1u << cols[2]) | (1u << cols[3]);

    int i = blockIdx.x * 256 + threadIdx.x;
    if (i >= n4) return;

    unsigned q = (unsigned)i % 196u;      // float4 index within the 28x28 image
    unsigned h = q / 7u;                  // row (28 rows, 7 float4s per row)
    unsigned w = (q - h * 7u) * 4u;       // base column of this float4

    // sel bit j = mute component j. Row hit mutes all 4; col hits are per-lane bits.
    unsigned sel = (((row_mask >> h) & 1u) ? 0xFu : 0u) | ((col_mask >> w) & 0xFu);

    float4 v = x[i];
    if (sel & 1u) v.x = mute1(v.x);
    if (sel & 2u) v.y = mute1(v.y);
    if (sel & 4u) v.z = mute1(v.z);
    if (sel & 8u) v.w = mute1(v.w);
    out[i] = v;
}

extern "C" void kernel_launch(void* const* d_in, const int* in_sizes, int n_in,
                              void* d_out, int out_size, void* d_ws, size_t ws_size,
                              hipStream_t stream) {
    const float* x   = (const float*)d_in[0];
    const int* rows  = (const int*)d_in[1];
    const int* cols  = (const int*)d_in[2];
    float* out       = (float*)d_out;

    int n  = in_sizes[0];          // 131072*28*28 = 102,760,448 (divisible by 4)
    int n4 = n / 4;                // 25,690,112
    int blocks = (n4 + 255) / 256; // 100,352 exactly

    mute_kernel<<<blocks, 256, 0, stream>>>(
        (const float4*)x, (float4*)out, rows, cols, n4);
}